// Round 7
// baseline (123.805 us; speedup 1.0000x reference)
//
#include <hip/hip_runtime.h>
#include <hip/hip_bf16.h>
#include <hip/hip_fp16.h>

#define BB 2
#define CC 4
#define KK 32
#define HHH 96
#define WWW 96
#define DDD 64
#define NN (DDD * DDD * DDD)   /* 262144 */
#define HWSZ (HHH * WWW)       /* 9216 */

// ---------------------------------------------------------------------------
// Kernel 1: transpose+convert heatmaps (B,C,K,H,W) fp32 -> (B,C,H,W,K) fp16.
// One bilinear corner's 32-k run is then a contiguous 64-byte line (one L1
// line), and the per-batch working set (2.35 MB) fits a 4 MB per-XCD L2.
// ---------------------------------------------------------------------------
__global__ __launch_bounds__(256) void hm_transpose_h(const float* __restrict__ in,
                                                      __half* __restrict__ out) {
  __shared__ float tile[KK][64 + 1];
  const int bc  = blockIdx.y;          // 0..B*C-1
  const int hw0 = blockIdx.x * 64;
  const int t   = threadIdx.x;

  const float* src = in + (size_t)bc * KK * HWSZ;
  const int lhw = t & 63, lk0 = t >> 6;
#pragma unroll
  for (int i = 0; i < 8; ++i) {
    const int k = lk0 + i * 4;
    tile[k][lhw] = src[(size_t)k * HWSZ + hw0 + lhw];   // coalesced 256B/wave
  }
  __syncthreads();

  __half* dst = out + ((size_t)bc * HWSZ + hw0) * KK;
  const int kp = (t & 15) * 2;         // k pair
  const int h0 = t >> 4;               // 16 hw per round
#pragma unroll
  for (int i = 0; i < 4; ++i) {
    const int h = h0 + i * 16;
    const __half2 hv = __floats2half2_rn(tile[kp][h], tile[kp + 1][h]);
    *(__half2*)(dst + (size_t)h * KK + kp) = hv;        // 64B/16-lane group
  }
}

// ---------------------------------------------------------------------------
// Kernel 2 (v4): two-phase, fp16 gather.
// Phase 1: 1 thread = 1 voxel; projection once per (voxel,cam); packed corner
//          offset u32 (off00 | dx<<14 | dy<<15) + masked float4 weights in LDS.
// Phase 2: 8 lanes = 1 voxel; lane j owns k=4j..4j+3 and loads 8B per corner
//          (the corner's 64B line is covered by the 8 lanes = 1 L1 line).
//          Per-cam skip when all weights zero. Output re-transposed through a
//          conflict-free LDS tile for 128B-coalesced stores.
// ---------------------------------------------------------------------------
__global__ __launch_bounds__(256) void unproject4(
    const __half* __restrict__ hmT,   // (B,C,H,W,K) fp16
    const float* __restrict__ Pm,     // (B,C,3,4)
    const float* __restrict__ coords, // (B,N,3)
    const float* __restrict__ conf,   // (B,C,K)
    float* __restrict__ out) {        // (B,K,N)
  __shared__ float        sP[CC * 12];
  __shared__ float        sConf[CC][KK];
  __shared__ unsigned int sOffP[CC][256];  // 4 KB
  __shared__ float4       sW[CC][256];     // 16 KB
  __shared__ float        vtile[32][KK + 1];

  const int t     = threadIdx.x;
  const int vbase = blockIdx.x * 256;     // global voxel base (b*N + n)
  const int b     = vbase >> 18;          // uniform per block
  const int nbase = vbase & (NN - 1);

  if (t < CC * 12) sP[t] = Pm[b * CC * 12 + t];
  if (t < KK) {
    const float c0 = conf[(b * CC + 0) * KK + t];
    const float c1 = conf[(b * CC + 1) * KK + t];
    const float c2 = conf[(b * CC + 2) * KK + t];
    const float c3 = conf[(b * CC + 3) * KK + t];
    const float s  = c0 + c1 + c2 + c3;
    sConf[0][t] = c0 / s;
    sConf[1][t] = c1 / s;
    sConf[2][t] = c2 / s;
    sConf[3][t] = c3 / s;
  }
  __syncthreads();

  // ---- Phase 1: projection for my voxel ----------------------------------
  {
    const float x = coords[(size_t)(vbase + t) * 3 + 0];
    const float y = coords[(size_t)(vbase + t) * 3 + 1];
    const float z = coords[(size_t)(vbase + t) * 3 + 2];
    // ix = (gx+1)*0.5*(W-1) with gx = 2*(u/H-0.5)  =>  ix = u*(W-1)/H
    const float sxc = (float)(WWW - 1) / (float)HHH;
    const float syc = (float)(HHH - 1) / (float)WWW;
#pragma unroll
    for (int c = 0; c < CC; ++c) {
      const float* P = &sP[c * 12];
      const float pz = P[8] * x + P[9] * y + P[10] * z + P[11];
      const float valid = (pz > 0.0f) ? 1.0f : 0.0f;
      const float zs    = (pz > 0.0f) ? pz : 1.0f;   // no inf/NaN ever
      const float px = P[0] * x + P[1] * y + P[2] * z + P[3];
      const float py = P[4] * x + P[5] * y + P[6] * z + P[7];
      const float u = px / zs, v2 = py / zs;
      const float ix = u * sxc, iy = v2 * syc;
      const float x0f = floorf(ix), y0f = floorf(iy);
      const float x1f = x0f + 1.0f, y1f = y0f + 1.0f;
      const float wx1 = ix - x0f, wx0 = 1.0f - wx1;
      const float wy1 = iy - y0f, wy0 = 1.0f - wy1;
      const float ibx0 = (x0f >= 0.f && x0f <= (float)(WWW - 1)) ? 1.f : 0.f;
      const float ibx1 = (x1f >= 0.f && x1f <= (float)(WWW - 1)) ? 1.f : 0.f;
      const float iby0 = (y0f >= 0.f && y0f <= (float)(HHH - 1)) ? 1.f : 0.f;
      const float iby1 = (y1f >= 0.f && y1f <= (float)(HHH - 1)) ? 1.f : 0.f;
      const int x0i = (int)fminf(fmaxf(x0f, 0.f), (float)(WWW - 1));
      const int x1i = (int)fminf(fmaxf(x1f, 0.f), (float)(WWW - 1));
      const int y0i = (int)fminf(fmaxf(y0f, 0.f), (float)(HHH - 1));
      const int y1i = (int)fminf(fmaxf(y1f, 0.f), (float)(HHH - 1));
      sOffP[c][t] = (unsigned int)(y0i * WWW + x0i) |
                    ((unsigned int)(x1i - x0i) << 14) |
                    ((unsigned int)(y1i - y0i) << 15);
      sW[c][t] = make_float4(wx0 * wy0 * (ibx0 * iby0 * valid),
                             wx1 * wy0 * (ibx1 * iby0 * valid),
                             wx0 * wy1 * (ibx0 * iby1 * valid),
                             wx1 * wy1 * (ibx1 * iby1 * valid));
    }
  }
  __syncthreads();

  // ---- Phase 2: cooperative fp16 gather ----------------------------------
  const int vloc = t >> 3;                // voxel-within-pass (0..31)
  const int j    = t & 7;                 // k-chunk (k = 4j..4j+3)

  float4 cf[CC];
#pragma unroll
  for (int c = 0; c < CC; ++c) cf[c] = ((const float4*)sConf[c])[j];

  const __half* base0 = hmT + (size_t)b * CC * HWSZ * KK + j * 4;
  float* ob = out + (size_t)b * KK * NN + nbase;

  for (int pass = 0; pass < 8; ++pass) {
    const int v = pass * 32 + vloc;
    float4 acc = make_float4(0.f, 0.f, 0.f, 0.f);
#pragma unroll
    for (int c = 0; c < CC; ++c) {
      const float4 w = sW[c][v];          // broadcast across the 8 lanes
      if (w.x + w.y + w.z + w.w > 0.0f) {
        const unsigned int p = sOffP[c][v];
        const int o00 = (int)(p & 0x3FFFu);
        const int dx  = (int)((p >> 14) & 1u);
        const int dyo = (int)((p >> 15) & 1u) * WWW;
        const __half* hp = base0 + (size_t)c * (HWSZ * KK);
        const uint2 q00 = *(const uint2*)(hp + (size_t)o00 * KK);
        const uint2 q01 = *(const uint2*)(hp + (size_t)(o00 + dx) * KK);
        const uint2 q10 = *(const uint2*)(hp + (size_t)(o00 + dyo) * KK);
        const uint2 q11 = *(const uint2*)(hp + (size_t)(o00 + dyo + dx) * KK);
        const float2 f00a = __half22float2(*(const __half2*)&q00.x);
        const float2 f00b = __half22float2(*(const __half2*)&q00.y);
        const float2 f01a = __half22float2(*(const __half2*)&q01.x);
        const float2 f01b = __half22float2(*(const __half2*)&q01.y);
        const float2 f10a = __half22float2(*(const __half2*)&q10.x);
        const float2 f10b = __half22float2(*(const __half2*)&q10.y);
        const float2 f11a = __half22float2(*(const __half2*)&q11.x);
        const float2 f11b = __half22float2(*(const __half2*)&q11.y);
        acc.x += (f00a.x * w.x + f01a.x * w.y + f10a.x * w.z + f11a.x * w.w) * cf[c].x;
        acc.y += (f00a.y * w.x + f01a.y * w.y + f10a.y * w.z + f11a.y * w.w) * cf[c].y;
        acc.z += (f00b.x * w.x + f01b.x * w.y + f10b.x * w.z + f11b.x * w.w) * cf[c].z;
        acc.w += (f00b.y * w.x + f01b.y * w.y + f10b.y * w.z + f11b.y * w.w) * cf[c].w;
      }
    }
    vtile[vloc][j * 4 + 0] = acc.x;
    vtile[vloc][j * 4 + 1] = acc.y;
    vtile[vloc][j * 4 + 2] = acc.z;
    vtile[vloc][j * 4 + 3] = acc.w;
    __syncthreads();
#pragma unroll
    for (int q = 0; q < 4; ++q) {
      const int idx = t + q * 256;
      const int k   = idx >> 5;
      const int n0  = idx & 31;
      ob[(size_t)k * NN + pass * 32 + n0] = vtile[n0][k];  // 2x128B per wave
    }
    __syncthreads();
  }
}

// ---------------------------------------------------------------------------
// Fallback (native layout, no workspace): one thread = one voxel, strided k.
// ---------------------------------------------------------------------------
__global__ __launch_bounds__(256) void unproject_native(
    const float* __restrict__ hm, const float* __restrict__ Pm,
    const float* __restrict__ coords, const float* __restrict__ conf,
    float* __restrict__ out) {
  __shared__ float sP[CC * 12];
  __shared__ float sConf[CC * KK];
  const int t   = threadIdx.x;
  const int gid = blockIdx.x * 256 + t;
  const int b   = gid >> 18;
  const int n   = gid & (NN - 1);
  if (t < CC * 12) sP[t] = Pm[b * CC * 12 + t];
  if (t < KK) {
    const float c0 = conf[(b * CC + 0) * KK + t];
    const float c1 = conf[(b * CC + 1) * KK + t];
    const float c2 = conf[(b * CC + 2) * KK + t];
    const float c3 = conf[(b * CC + 3) * KK + t];
    const float s  = c0 + c1 + c2 + c3;
    sConf[0 * KK + t] = c0 / s; sConf[1 * KK + t] = c1 / s;
    sConf[2 * KK + t] = c2 / s; sConf[3 * KK + t] = c3 / s;
  }
  __syncthreads();
  const float x = coords[(size_t)gid * 3 + 0];
  const float y = coords[(size_t)gid * 3 + 1];
  const float z = coords[(size_t)gid * 3 + 2];
  float accs[KK];
#pragma unroll
  for (int k = 0; k < KK; ++k) accs[k] = 0.f;
  const float sxc = (float)(WWW - 1) / (float)HHH;
  const float syc = (float)(HHH - 1) / (float)WWW;
#pragma unroll
  for (int c = 0; c < CC; ++c) {
    const float* P = &sP[c * 12];
    const float pz = P[8] * x + P[9] * y + P[10] * z + P[11];
    if (pz > 0.0f) {
      const float px = P[0] * x + P[1] * y + P[2] * z + P[3];
      const float py = P[4] * x + P[5] * y + P[6] * z + P[7];
      const float u = px / pz, v2 = py / pz;
      const float ix = u * sxc, iy = v2 * syc;
      const float x0f = floorf(ix), y0f = floorf(iy);
      const float x1f = x0f + 1.0f, y1f = y0f + 1.0f;
      const float wx1 = ix - x0f, wx0 = 1.0f - wx1;
      const float wy1 = iy - y0f, wy0 = 1.0f - wy1;
      const float ibx0 = (x0f >= 0.f && x0f <= (float)(WWW - 1)) ? 1.f : 0.f;
      const float ibx1 = (x1f >= 0.f && x1f <= (float)(WWW - 1)) ? 1.f : 0.f;
      const float iby0 = (y0f >= 0.f && y0f <= (float)(HHH - 1)) ? 1.f : 0.f;
      const float iby1 = (y1f >= 0.f && y1f <= (float)(HHH - 1)) ? 1.f : 0.f;
      const float w00 = wx0 * wy0 * ibx0 * iby0;
      const float w01 = wx1 * wy0 * ibx1 * iby0;
      const float w10 = wx0 * wy1 * ibx0 * iby1;
      const float w11 = wx1 * wy1 * ibx1 * iby1;
      const int x0i = (int)fminf(fmaxf(x0f, 0.f), (float)(WWW - 1));
      const int x1i = (int)fminf(fmaxf(x1f, 0.f), (float)(WWW - 1));
      const int y0i = (int)fminf(fmaxf(y0f, 0.f), (float)(HHH - 1));
      const int y1i = (int)fminf(fmaxf(y1f, 0.f), (float)(HHH - 1));
      const float* bse = hm + (size_t)(b * CC + c) * KK * HWSZ;
      const int i00 = y0i * WWW + x0i, i01 = y0i * WWW + x1i;
      const int i10 = y1i * WWW + x0i, i11 = y1i * WWW + x1i;
#pragma unroll
      for (int k = 0; k < KK; ++k) {
        const float* hk = bse + (size_t)k * HWSZ;
        accs[k] += (hk[i00] * w00 + hk[i01] * w01 +
                    hk[i10] * w10 + hk[i11] * w11) * sConf[c * KK + k];
      }
    }
  }
  float* ob = out + (size_t)b * KK * NN + n;
#pragma unroll
  for (int k = 0; k < KK; ++k) ob[(size_t)k * NN] = accs[k];
}

extern "C" void kernel_launch(void* const* d_in, const int* in_sizes, int n_in,
                              void* d_out, int out_size, void* d_ws, size_t ws_size,
                              hipStream_t stream) {
  const float* heatmaps = (const float*)d_in[0];  // (B,C,K,H,W)
  const float* Pm       = (const float*)d_in[1];  // (B,C,3,4)
  const float* coords   = (const float*)d_in[2];  // (B,D,D,D,3)
  const float* conf     = (const float*)d_in[3];  // (B,C,K)
  float* out            = (float*)d_out;          // (B,K,D,D,D)

  const size_t hmT_bytes = (size_t)BB * CC * HWSZ * KK * sizeof(__half); // 4.7 MB

  if (ws_size >= hmT_bytes) {
    __half* hmT = (__half*)d_ws;
    dim3 tg(HWSZ / 64, BB * CC);                  // (144, 8)
    hm_transpose_h<<<tg, 256, 0, stream>>>(heatmaps, hmT);
    const int grid = (BB * NN) / 256;             // 2048 blocks, 256 voxels each
    unproject4<<<grid, 256, 0, stream>>>(hmT, Pm, coords, conf, out);
  } else {
    const int grid = (BB * NN) / 256;
    unproject_native<<<grid, 256, 0, stream>>>(heatmaps, Pm, coords, conf, out);
  }
}